// Round 4
// baseline (142.937 us; speedup 1.0000x reference)
//
#include <hip/hip_runtime.h>

#define WI 512
#define HI 512
#define WO 2048
#define HO 2048
#define NIMG 8
#define CCH 3
#define EPS 1e-8f
#define PLANE (HI * WI)

#define TPB  256      // threads per block
#define SEG  1024     // output px per block (half row)
#define PXT  4        // CONSECUTIVE px per thread

// ===========================================================================
// v12: no-staging gather kernel. The v8..v11 LDS pipeline (load->commit->
// barrier->blend per image) was latency-serialized with every pipe <30% busy.
// Per-block src working set is <=12KB/image (L1-resident; src total 25MB is
// L2/L3-resident), so we gather the 2x2 bilinear taps directly from global
// through L1: 12 independent dword loads + ~20 VALU per px per layer, no LDS
// data path, no barriers after setup, deep MLP instead of a hand pipeline.
//  - per-image uniform state computed once (tid<8) into tiny LDS, 1 barrier
//  - wave-granular visibility + interior classification (monotone-fma span
//    proof as v11) and wave-granular occlusion: topmost layer with my==1
//    covering this wave's 256 px culls all layers below it AND the bg read
//    (exact: m==1 -> om==0 -> replace).
//  - sampling formulas byte-identical to v11's verified paths.
// ===========================================================================
__launch_bounds__(TPB)
__global__ void diffcomp_v12(const float* __restrict__ src,
                             const float* __restrict__ bg,
                             const float* __restrict__ coor,
                             float* __restrict__ out) {
    __shared__ float4 stY[NIMG];   // (wy0, wy1, y0o_f, y1o_f)
    __shared__ float4 stX[NIMG];   // (A2, D, my, valid_f)

    const int tid = threadIdx.x;
    const int b0  = blockIdx.x;
    const int b   = ((b0 & 7) << 9) | (b0 >> 3);       // bijective XCD swizzle
    const int row = b >> 1;
    const int wo0 = (b & 1) << 10;
    const float ys  = (2.0f * (float)row + 1.0f) / (float)HO - 1.0f;
    const float HW1 = 0.5f * (float)(WI - 1);          // 255.5

    if (tid < NIMG) {
        const float cx  = coor[tid * 4 + 0];
        const float cy  = coor[tid * 4 + 1];
        const float cw  = coor[tid * 4 + 2];
        const float chh = coor[tid * 4 + 3];
        const float xx = (1.0f / (1.0f + expf(-cx))) * (float)WO;
        const float yy = (1.0f / (1.0f + expf(-cy))) * (float)HO;
        const float w  = (1.0f / (1.0f + expf(-cw))) * (float)WO;
        const float h  = (1.0f / (1.0f + expf(-chh))) * (float)HO;
        const float a  = (float)WO / (w + EPS);
        const float bb = (float)HO / (h + EPS);
        const float ty = (2.0f / (float)HO) * ((float)HO * 0.5f - yy) * bb;

        // y chain (reference form, as v10/v11)
        const float gy  = bb * ys + ty;
        const float iy  = ((gy + 1.0f) * (float)HI - 1.0f) * 0.5f;
        const float y0f = floorf(iy);
        const float fy1 = iy - y0f;
        const float fy0 = 1.0f - fy1;
        const float y1f = y0f + 1.0f;
        const float v0  = (y0f >= 0.0f && y0f < (float)HI) ? 1.0f : 0.0f;
        const float v1  = (y1f >= 0.0f && y1f < (float)HI) ? 1.0f : 0.0f;
        const float wy0 = fy0 * v0;
        const float wy1 = fy1 * v1;
        const float my  = wy0 + wy1;
        const float y0of = fminf(fmaxf(y0f, 0.0f), (float)(HI - 1)) * (float)WI;
        const float y1of = fminf(fmaxf(y1f, 0.0f), (float)(HI - 1)) * (float)WI;

        // x mapping: ix(wo) = A2*(wo + D) + HW1
        const float A2 = a * ((float)WI / (float)WO);
        const float D  = 0.5f - xx;

        float validf = 0.0f;
        if (my > 0.0f) {
            const float ixf = fmaf(A2, (float)wo0 + D, HW1);
            const float ixl = fmaf(A2, (float)(wo0 + SEG - 1) + D, HW1);
            if (!(ixl <= -1.0f || ixf >= (float)WI)) validf = 1.0f;
        }
        stY[tid] = make_float4(wy0, wy1, y0of, y1of);
        stX[tid] = make_float4(A2, D, my, validf);
    }
    __syncthreads();

    // ---- wave-granular visibility / interior / occlusion masks (uniform) ----
    const int pw0 = wo0 + ((tid >> 6) << 8);           // wave's 256-px window
    unsigned wvis = 0u, wintr = 0u;
    int jw = -1;                                       // topmost full-cover layer
#pragma unroll
    for (int n = 0; n < NIMG; n++) {
        const float4 SX = stX[n];
        if (SX.w > 0.0f) {
            const float ixF = fmaf(SX.x, (float)pw0 + SX.y, HW1);
            const float ixL = fmaf(SX.x, (float)(pw0 + 255) + SX.y, HW1);
            if (!(ixL <= -1.0f || ixF >= (float)WI)) {
                wvis |= (1u << n);
                if (ixF >= 0.0f && ixL < (float)(WI - 1)) {
                    wintr |= (1u << n);
                    if (SX.z == 1.0f) jw = n;          // my==1 exact (see v10)
                }
            }
        }
    }
    if (jw >= 0) wvis &= ~((1u << jw) - 1u);           // layers below jw hidden

    const int px0   = wo0 + (tid << 2);
    const int gbase = row * WO + px0;

    float acc[CCH][PXT];
    if (jw < 0) {
#pragma unroll
        for (int c = 0; c < CCH; c++) {
            const float4 bv = *(const float4*)&bg[c * (HO * WO) + gbase];
            acc[c][0] = bv.x; acc[c][1] = bv.y; acc[c][2] = bv.z; acc[c][3] = bv.w;
        }
    } else {
#pragma unroll
        for (int c = 0; c < CCH; c++)
#pragma unroll
            for (int p = 0; p < PXT; p++)
                acc[c][p] = 0.0f;
    }

    float xpf[PXT];
#pragma unroll
    for (int p = 0; p < PXT; p++) xpf[p] = (float)(px0 + p);

    // ---- blend loop: back-to-front over visible layers, no barriers ----
    while (wvis) {
        const int n = (int)__builtin_ctz(wvis);
        wvis &= wvis - 1u;
        const float4 SX = stX[n];
        const float4 SY = stY[n];
        const float A2 = SX.x, Dv = SX.y, my = SX.z;
        const float wy0 = SY.x, wy1 = SY.y;
        const int y0o = (int)SY.z;
        const int y1o = (int)SY.w;
        const float* ib = src + n * (CCH * PLANE);

        if ((wintr >> n) & 1u) {
            // interior: k, k+1 in-bounds for every px of this wave (monotone fma)
            const float omy = 1.0f - my;
            if (omy == 0.0f) {                         // my==1: pure replace
#pragma unroll
                for (int p = 0; p < PXT; p++) {
                    const float ix  = fmaf(A2, xpf[p] + Dv, HW1);
                    const float x0f = floorf(ix);
                    const float fx1 = ix - x0f;
                    const int   k   = (int)x0f;
                    const float* p0 = ib + y0o + k;
                    const float* p1 = ib + y1o + k;
#pragma unroll
                    for (int c = 0; c < CCH; c++) {
                        const float r00 = p0[c * PLANE];
                        const float r01 = p0[c * PLANE + 1];
                        const float r10 = p1[c * PLANE];
                        const float r11 = p1[c * PLANE + 1];
                        const float q0 = r00 * wy0 + r10 * wy1;
                        const float q1 = r01 * wy0 + r11 * wy1;
                        acc[c][p] = q0 + fx1 * (q1 - q0);
                    }
                }
            } else {                                   // y-edge row: uniform m=my
#pragma unroll
                for (int p = 0; p < PXT; p++) {
                    const float ix  = fmaf(A2, xpf[p] + Dv, HW1);
                    const float x0f = floorf(ix);
                    const float fx1 = ix - x0f;
                    const int   k   = (int)x0f;
                    const float* p0 = ib + y0o + k;
                    const float* p1 = ib + y1o + k;
#pragma unroll
                    for (int c = 0; c < CCH; c++) {
                        const float r00 = p0[c * PLANE];
                        const float r01 = p0[c * PLANE + 1];
                        const float r10 = p1[c * PLANE];
                        const float r11 = p1[c * PLANE + 1];
                        const float q0 = r00 * wy0 + r10 * wy1;
                        const float q1 = r01 * wy0 + r11 * wy1;
                        const float sc = q0 + fx1 * (q1 - q0);
                        acc[c][p] = acc[c][p] * omy + my * sc;
                    }
                }
            }
        } else {
            // boundary wave: full reference math with clamps (rare)
#pragma unroll
            for (int p = 0; p < PXT; p++) {
                const float ix  = fmaf(A2, xpf[p] + Dv, HW1);
                const float x0f = floorf(ix);
                const float fx1 = ix - x0f;
                const float fx0 = 1.0f - fx1;
                const float x1f = x0f + 1.0f;
                const float v0  = (x0f >= 0.0f && x0f < (float)WI) ? 1.0f : 0.0f;
                const float v1  = (x1f >= 0.0f && x1f < (float)WI) ? 1.0f : 0.0f;
                const float wx0 = fx0 * v0;
                const float wx1 = fx1 * v1;
                const int x0c = (int)fminf(fmaxf(x0f, 0.0f), (float)(WI - 1));
                const int x1c = (int)fminf(fmaxf(x1f, 0.0f), (float)(WI - 1));
                const float m  = my * (wx0 + wx1);
                const float om = 1.0f - m;
#pragma unroll
                for (int c = 0; c < CCH; c++) {
                    const float* cb = ib + c * PLANE;
                    const float q00 = cb[y0o + x0c];
                    const float q10 = cb[y1o + x0c];
                    const float q01 = cb[y0o + x1c];
                    const float q11 = cb[y1o + x1c];
                    const float q0 = q00 * wy0 + q10 * wy1;
                    const float q1 = q01 * wy0 + q11 * wy1;
                    const float sc = q0 * wx0 + q1 * wx1;
                    acc[c][p] = acc[c][p] * om + sc * m;
                }
            }
        }
    }

#pragma unroll
    for (int c = 0; c < CCH; c++)
        *(float4*)&out[c * (HO * WO) + gbase] =
            make_float4(acc[c][0], acc[c][1], acc[c][2], acc[c][3]);
}

extern "C" void kernel_launch(void* const* d_in, const int* in_sizes, int n_in,
                              void* d_out, int out_size, void* d_ws, size_t ws_size,
                              hipStream_t stream) {
    const float* src  = (const float*)d_in[0];   // [8,3,512,512]
    const float* bg   = (const float*)d_in[1];   // [1,3,2048,2048]
    const float* coor = (const float*)d_in[2];   // [8,4]
    float* out = (float*)d_out;                  // [1,3,2048,2048]
    (void)d_ws; (void)ws_size;

    hipLaunchKernelGGL(diffcomp_v12, dim3(HO * (WO / SEG)), dim3(TPB), 0, stream,
                       src, bg, coor, out);
}

// Round 5
// 140.050 us; speedup vs baseline: 1.0206x; 1.0206x over previous
//
#include <hip/hip_runtime.h>

#define WI 512
#define HI 512
#define WO 2048
#define HO 2048
#define NIMG 8
#define CCH 3
#define EPS 1e-8f
#define PLANE (HI * WI)

#define TPB  256      // threads per block
#define SEG  1024     // output px per segment (half row)
#define PXT  4        // CONSECUTIVE px per thread
#define SEGS 4        // segments per workgroup (2 consecutive rows x 2 halves)
#define NWG  (HO * (WO / SEG) / SEGS)   // 1024 workgroups

// ===========================================================================
// v13: v12's verified no-barrier gather body, but 4 segments per workgroup.
// Rounds 0-4 showed time invariant (44-52us) across 5 structures with every
// pipe <30% busy and occupancy 23-40% at zero resource pressure => the cost
// is per-workgroup fixed overhead (launch/setup/drain of 4096 tiny WGs), not
// any data pipe. v13 amortizes it 4x and quadruples per-thread MLP:
//  - grid 1024 WGs; each WG owns 4 consecutive segments (2 rows x 2 halves)
//  - setup once per WG (tid<8: sigmoids + y-state for both rows), 1 barrier
//  - fully unrolled 4-segment loop, no barriers: independent load chains
//    from all 4 segments overlap in flight
//  - consecutive rows share src rows -> L1/L2 reuse
//  - sampling math byte-identical to v12's verified paths
// ===========================================================================
__launch_bounds__(TPB, 4)
__global__ void diffcomp_v13(const float* __restrict__ src,
                             const float* __restrict__ bg,
                             const float* __restrict__ coor,
                             float* __restrict__ out) {
    __shared__ float4 stA[NIMG];       // (A2, D, my_row0, my_row1)
    __shared__ float4 stY[2][NIMG];    // (wy0, wy1, y0o_f, y1o_f) per row parity

    const int tid = threadIdx.x;
    const int wg0 = blockIdx.x;
    const int wg  = ((wg0 & 7) << 7) | (wg0 >> 3);  // bijective XCD chunk swizzle
    const int segbase = wg << 2;                    // 4 consecutive segments
    const int row0 = segbase >> 1;                  // first of the WG's 2 rows
    const float HW1 = 0.5f * (float)(WI - 1);       // 255.5

    if (tid < NIMG) {
        const float cx  = coor[tid * 4 + 0];
        const float cy  = coor[tid * 4 + 1];
        const float cw  = coor[tid * 4 + 2];
        const float chh = coor[tid * 4 + 3];
        const float xx = (1.0f / (1.0f + expf(-cx))) * (float)WO;
        const float yy = (1.0f / (1.0f + expf(-cy))) * (float)HO;
        const float w  = (1.0f / (1.0f + expf(-cw))) * (float)WO;
        const float h  = (1.0f / (1.0f + expf(-chh))) * (float)HO;
        const float a  = (float)WO / (w + EPS);
        const float bb = (float)HO / (h + EPS);
        const float ty = (2.0f / (float)HO) * ((float)HO * 0.5f - yy) * bb;

        // x mapping: ix(wo) = A2*(wo + D) + HW1
        const float A2 = a * ((float)WI / (float)WO);
        const float D  = 0.5f - xx;

        float myv[2];
#pragma unroll
        for (int r = 0; r < 2; r++) {
            const float ys  = (2.0f * (float)(row0 + r) + 1.0f) / (float)HO - 1.0f;
            const float gy  = bb * ys + ty;
            const float iy  = ((gy + 1.0f) * (float)HI - 1.0f) * 0.5f;
            const float y0f = floorf(iy);
            const float fy1 = iy - y0f;
            const float fy0 = 1.0f - fy1;
            const float y1f = y0f + 1.0f;
            const float v0  = (y0f >= 0.0f && y0f < (float)HI) ? 1.0f : 0.0f;
            const float v1  = (y1f >= 0.0f && y1f < (float)HI) ? 1.0f : 0.0f;
            const float wy0 = fy0 * v0;
            const float wy1 = fy1 * v1;
            myv[r] = wy0 + wy1;
            const float y0of = fminf(fmaxf(y0f, 0.0f), (float)(HI - 1)) * (float)WI;
            const float y1of = fminf(fmaxf(y1f, 0.0f), (float)(HI - 1)) * (float)WI;
            stY[r][tid] = make_float4(wy0, wy1, y0of, y1of);
        }
        stA[tid] = make_float4(A2, D, myv[0], myv[1]);
    }
    __syncthreads();

#pragma unroll
    for (int s = 0; s < SEGS; s++) {
        const int row = row0 + (s >> 1);
        const int rp  = s >> 1;                       // row-parity index
        const int wo0 = (s & 1) << 10;                // half-row offset

        // ---- wave-granular visibility / interior / occlusion (uniform) ----
        const int pw0 = wo0 + ((tid >> 6) << 8);      // wave's 256-px window
        unsigned wvis = 0u, wintr = 0u;
        int jw = -1;                                  // topmost full-cover layer
#pragma unroll
        for (int n = 0; n < NIMG; n++) {
            const float4 SA = stA[n];
            const float myn = rp ? SA.w : SA.z;
            if (myn > 0.0f) {
                const float ixF = fmaf(SA.x, (float)pw0 + SA.y, HW1);
                const float ixL = fmaf(SA.x, (float)(pw0 + 255) + SA.y, HW1);
                if (!(ixL <= -1.0f || ixF >= (float)WI)) {
                    wvis |= (1u << n);
                    if (ixF >= 0.0f && ixL < (float)(WI - 1)) {
                        wintr |= (1u << n);
                        if (myn == 1.0f) jw = n;      // my==1 exact (see v10)
                    }
                }
            }
        }
        if (jw >= 0) wvis &= ~((1u << jw) - 1u);      // layers below jw hidden

        const int px0   = wo0 + (tid << 2);
        const int gbase = row * WO + px0;

        float acc[CCH][PXT];
        if (jw < 0) {
#pragma unroll
            for (int c = 0; c < CCH; c++) {
                const float4 bv = *(const float4*)&bg[c * (HO * WO) + gbase];
                acc[c][0] = bv.x; acc[c][1] = bv.y; acc[c][2] = bv.z; acc[c][3] = bv.w;
            }
        } else {
#pragma unroll
            for (int c = 0; c < CCH; c++)
#pragma unroll
                for (int p = 0; p < PXT; p++)
                    acc[c][p] = 0.0f;
        }

        float xpf[PXT];
#pragma unroll
        for (int p = 0; p < PXT; p++) xpf[p] = (float)(px0 + p);

        // ---- blend: back-to-front over visible layers, no barriers ----
        while (wvis) {
            const int n = (int)__builtin_ctz(wvis);
            wvis &= wvis - 1u;
            const float4 SA = stA[n];
            const float4 SY = stY[rp][n];
            const float A2 = SA.x, Dv = SA.y;
            const float my = rp ? SA.w : SA.z;
            const float wy0 = SY.x, wy1 = SY.y;
            const int y0o = (int)SY.z;
            const int y1o = (int)SY.w;
            const float* ib = src + n * (CCH * PLANE);

            if ((wintr >> n) & 1u) {
                // interior: k, k+1 in-bounds for every px (monotone fma proof)
                const float omy = 1.0f - my;
                if (omy == 0.0f) {                    // my==1: pure replace
#pragma unroll
                    for (int p = 0; p < PXT; p++) {
                        const float ix  = fmaf(A2, xpf[p] + Dv, HW1);
                        const float x0f = floorf(ix);
                        const float fx1 = ix - x0f;
                        const int   k   = (int)x0f;
                        const float* p0 = ib + y0o + k;
                        const float* p1 = ib + y1o + k;
#pragma unroll
                        for (int c = 0; c < CCH; c++) {
                            const float r00 = p0[c * PLANE];
                            const float r01 = p0[c * PLANE + 1];
                            const float r10 = p1[c * PLANE];
                            const float r11 = p1[c * PLANE + 1];
                            const float q0 = r00 * wy0 + r10 * wy1;
                            const float q1 = r01 * wy0 + r11 * wy1;
                            acc[c][p] = q0 + fx1 * (q1 - q0);
                        }
                    }
                } else {                              // y-edge row: uniform m=my
#pragma unroll
                    for (int p = 0; p < PXT; p++) {
                        const float ix  = fmaf(A2, xpf[p] + Dv, HW1);
                        const float x0f = floorf(ix);
                        const float fx1 = ix - x0f;
                        const int   k   = (int)x0f;
                        const float* p0 = ib + y0o + k;
                        const float* p1 = ib + y1o + k;
#pragma unroll
                        for (int c = 0; c < CCH; c++) {
                            const float r00 = p0[c * PLANE];
                            const float r01 = p0[c * PLANE + 1];
                            const float r10 = p1[c * PLANE];
                            const float r11 = p1[c * PLANE + 1];
                            const float q0 = r00 * wy0 + r10 * wy1;
                            const float q1 = r01 * wy0 + r11 * wy1;
                            const float sc = q0 + fx1 * (q1 - q0);
                            acc[c][p] = acc[c][p] * omy + my * sc;
                        }
                    }
                }
            } else {
                // boundary wave: full reference math with clamps (rare)
#pragma unroll
                for (int p = 0; p < PXT; p++) {
                    const float ix  = fmaf(A2, xpf[p] + Dv, HW1);
                    const float x0f = floorf(ix);
                    const float fx1 = ix - x0f;
                    const float fx0 = 1.0f - fx1;
                    const float x1f = x0f + 1.0f;
                    const float v0  = (x0f >= 0.0f && x0f < (float)WI) ? 1.0f : 0.0f;
                    const float v1  = (x1f >= 0.0f && x1f < (float)WI) ? 1.0f : 0.0f;
                    const float wx0 = fx0 * v0;
                    const float wx1 = fx1 * v1;
                    const int x0c = (int)fminf(fmaxf(x0f, 0.0f), (float)(WI - 1));
                    const int x1c = (int)fminf(fmaxf(x1f, 0.0f), (float)(WI - 1));
                    const float m  = my * (wx0 + wx1);
                    const float om = 1.0f - m;
#pragma unroll
                    for (int c = 0; c < CCH; c++) {
                        const float* cb = ib + c * PLANE;
                        const float q00 = cb[y0o + x0c];
                        const float q10 = cb[y1o + x0c];
                        const float q01 = cb[y0o + x1c];
                        const float q11 = cb[y1o + x1c];
                        const float q0 = q00 * wy0 + q10 * wy1;
                        const float q1 = q01 * wy0 + q11 * wy1;
                        const float sc = q0 * wx0 + q1 * wx1;
                        acc[c][p] = acc[c][p] * om + sc * m;
                    }
                }
            }
        }

#pragma unroll
        for (int c = 0; c < CCH; c++)
            *(float4*)&out[c * (HO * WO) + gbase] =
                make_float4(acc[c][0], acc[c][1], acc[c][2], acc[c][3]);
    }
}

extern "C" void kernel_launch(void* const* d_in, const int* in_sizes, int n_in,
                              void* d_out, int out_size, void* d_ws, size_t ws_size,
                              hipStream_t stream) {
    const float* src  = (const float*)d_in[0];   // [8,3,512,512]
    const float* bg   = (const float*)d_in[1];   // [1,3,2048,2048]
    const float* coor = (const float*)d_in[2];   // [8,4]
    float* out = (float*)d_out;                  // [1,3,2048,2048]
    (void)d_ws; (void)ws_size;

    hipLaunchKernelGGL(diffcomp_v13, dim3(NWG), dim3(TPB), 0, stream,
                       src, bg, coor, out);
}

// Round 6
// 127.530 us; speedup vs baseline: 1.1208x; 1.0982x over previous
//
#include <hip/hip_runtime.h>

#define WI 512
#define HI 512
#define WO 2048
#define HO 2048
#define NIMG 8
#define CCH 3
#define EPS 1e-8f
#define PLANE (HI * WI)

#define TPB   512     // 8 waves per WG, one output row per WG
#define NWAVE 8
#define WPX   256     // px per wave window
#define PXT   4       // consecutive px per thread
#define CAPW  520     // texel slots per wave-private LDS slot

// ===========================================================================
// v14: wave-autonomous pipelines. Six structures (r0-r5) pinned at 44-52us
// with every pipe <31% busy; v13's VALUBusy 18% @ ~26% occupancy implies ~1
// effectively-running wave/SIMD: resident waves stall on CORRELATED events
// (block-wide barriers / lockstep waits), so TLP never applied. v14 makes
// the wave the unit: 8 waves/WG, each with a private 256-px window and a
// private 520-texel LDS slot; each wave stages its own layer rows (6-12
// contiguous dwordx4 loads), y-lerps, ds_writes, blends -- ZERO barriers
// after setup (within-wave ds ordering via compiler lgkmcnt; no cross-wave
// LDS sharing). ~24 independent wave-pipelines per CU decorrelate stalls.
//  - sampling math expression-identical to v11/v13's verified paths
//  - wave-granular occlusion cull (topmost my==1 interior layer jw hides
//    lower layers and the bg read; exact, validated r2-r5)
//  - texel-major slot: blend reads (k,k+1) pairs ds_read2-mergeable
//  - XCD swizzle keeps each XCD on a contiguous row band (2048 = 8*256)
// ===========================================================================
__launch_bounds__(TPB)
__global__ void diffcomp_v14(const float* __restrict__ src,
                             const float* __restrict__ bg,
                             const float* __restrict__ coor,
                             float* __restrict__ out) {
    __shared__ __align__(16) float cs[NWAVE][CAPW * CCH];   // 49,920 B
    __shared__ float4 stA[NIMG];   // (A2, D, my, wy0)
    __shared__ float4 stY[NIMG];   // (wy1, y0o_f, y1o_f, 0)

    const int tid = threadIdx.x;
    const int b0  = blockIdx.x;
    const int row = ((b0 & 7) << 8) | (b0 >> 3);   // bijective XCD swizzle
    const float HW1 = 0.5f * (float)(WI - 1);      // 255.5

    if (tid < NIMG) {
        const float cx  = coor[tid * 4 + 0];
        const float cy  = coor[tid * 4 + 1];
        const float cw  = coor[tid * 4 + 2];
        const float chh = coor[tid * 4 + 3];
        const float xx = (1.0f / (1.0f + expf(-cx))) * (float)WO;
        const float yy = (1.0f / (1.0f + expf(-cy))) * (float)HO;
        const float w  = (1.0f / (1.0f + expf(-cw))) * (float)WO;
        const float h  = (1.0f / (1.0f + expf(-chh))) * (float)HO;
        const float a  = (float)WO / (w + EPS);
        const float bb = (float)HO / (h + EPS);
        const float ty = (2.0f / (float)HO) * ((float)HO * 0.5f - yy) * bb;

        // y chain (reference form, verified r2-r5)
        const float ys  = (2.0f * (float)row + 1.0f) / (float)HO - 1.0f;
        const float gy  = bb * ys + ty;
        const float iy  = ((gy + 1.0f) * (float)HI - 1.0f) * 0.5f;
        const float y0f = floorf(iy);
        const float fy1 = iy - y0f;
        const float fy0 = 1.0f - fy1;
        const float y1f = y0f + 1.0f;
        const float v0  = (y0f >= 0.0f && y0f < (float)HI) ? 1.0f : 0.0f;
        const float v1  = (y1f >= 0.0f && y1f < (float)HI) ? 1.0f : 0.0f;
        const float wy0 = fy0 * v0;
        const float wy1 = fy1 * v1;
        const float my  = wy0 + wy1;
        const float y0of = fminf(fmaxf(y0f, 0.0f), (float)(HI - 1)) * (float)WI;
        const float y1of = fminf(fmaxf(y1f, 0.0f), (float)(HI - 1)) * (float)WI;

        // x mapping: ix(wo) = A2*(wo + D) + HW1
        const float A2 = a * ((float)WI / (float)WO);
        const float D  = 0.5f - xx;

        stA[tid] = make_float4(A2, D, my, wy0);
        stY[tid] = make_float4(wy1, y0of, y1of, 0.0f);
    }
    __syncthreads();          // the ONLY barrier

    const int wid  = tid >> 6;
    const int lane = tid & 63;
    const int pw0  = wid << 8;                 // wave's first px of the row
    const int px0  = pw0 + (lane << 2);
    const int gbase = row * WO + px0;

    // ---- wave-granular visibility / interior / occlusion (wave-uniform) ----
    unsigned wvis = 0u, wintr = 0u;
    int jw = -1;
#pragma unroll
    for (int n = 0; n < NIMG; n++) {
        const float4 SA = stA[n];
        if (SA.z > 0.0f) {
            const float ixF = fmaf(SA.x, (float)pw0 + SA.y, HW1);
            const float ixL = fmaf(SA.x, (float)(pw0 + WPX - 1) + SA.y, HW1);
            if (!(ixL <= -1.0f || ixF >= (float)WI)) {
                wvis |= (1u << n);
                if (ixF >= 0.0f && ixL < (float)(WI - 1)) {
                    wintr |= (1u << n);
                    if (SA.z == 1.0f) jw = n;   // my==1 exact => m==1 on wave
                }
            }
        }
    }
    if (jw >= 0) wvis &= ~((1u << jw) - 1u);    // layers below jw are hidden

    float acc[CCH][PXT];
    if (jw < 0) {
#pragma unroll
        for (int c = 0; c < CCH; c++) {
            const float4 bv = *(const float4*)&bg[c * (HO * WO) + gbase];
            acc[c][0] = bv.x; acc[c][1] = bv.y; acc[c][2] = bv.z; acc[c][3] = bv.w;
        }
    } else {
#pragma unroll
        for (int c = 0; c < CCH; c++)
#pragma unroll
            for (int p = 0; p < PXT; p++)
                acc[c][p] = 0.0f;
    }

    float xpf[PXT];
#pragma unroll
    for (int p = 0; p < PXT; p++) xpf[p] = (float)(px0 + p);

    float* const slot = cs[wid];               // wave-private texel slot

    // ---- layer loop: back-to-front, fully wave-local, no barriers ----
    while (wvis) {
        const int n = (int)__builtin_ctz(wvis);
        wvis &= wvis - 1u;
        const float4 SA = stA[n];
        const float4 SY = stY[n];
        const float A2 = SA.x, Dv = SA.y, my = SA.z;
        const float wy0 = SA.w, wy1 = SY.x;
        const int y0o = (int)SY.y;
        const int y1o = (int)SY.z;

        // wave-window staging range (v11 segment math at wave granularity)
        const float ixF = fmaf(A2, (float)pw0 + Dv, HW1);
        const float ixL = fmaf(A2, (float)(pw0 + WPX - 1) + Dv, HW1);
        const int t0  = (int)fminf(fmaxf(floorf(ixF), 0.0f), (float)(WI - 1));
        const int t1  = (int)fminf(fmaxf(floorf(ixL) + 1.0f, 0.0f), (float)(WI - 1));
        const int t0a = t0 & ~3;
        int R = (t1 - t0a + 4) & ~3;
        if (R > WI - t0a) R = WI - t0a;
        const int lim = t1 - t0a;

        const float* ib = src + n * (CCH * PLANE) + t0a;

        // stage: up to 2 sweeps x 256 texels, contiguous dwordx4, y-lerp,
        // texel-major ds_write into the wave's private slot
#pragma unroll
        for (int sw = 0; sw < 2; sw++) {
            const int xo = (lane << 2) + (sw << 8);
            if (xo < R) {
                float4 r0[CCH], r1[CCH];
#pragma unroll
                for (int c = 0; c < CCH; c++) {
                    r0[c] = *(const float4*)(ib + c * PLANE + y0o + xo);
                    r1[c] = *(const float4*)(ib + c * PLANE + y1o + xo);
                }
                float wv[12];
#pragma unroll
                for (int t = 0; t < 4; t++)
#pragma unroll
                    for (int c = 0; c < CCH; c++)
                        wv[t * CCH + c] = ((const float*)&r0[c])[t] * wy0
                                        + ((const float*)&r1[c])[t] * wy1;
                float* dst = &slot[xo * CCH];
                ((float4*)dst)[0] = make_float4(wv[0], wv[1], wv[2],  wv[3]);
                ((float4*)dst)[1] = make_float4(wv[4], wv[5], wv[6],  wv[7]);
                ((float4*)dst)[2] = make_float4(wv[8], wv[9], wv[10], wv[11]);
            }
        }
        // compiler inserts lgkmcnt before dependent ds_reads (within-wave dep)

        const float t0af = (float)t0a;
        if ((wintr >> n) & 1u) {
            // interior: k,k+1 in [0,lim] for every px (monotone fma proof)
            const float omy = 1.0f - my;
            if (omy == 0.0f) {                  // my==1: pure replace
#pragma unroll
                for (int p = 0; p < PXT; p++) {
                    const float ix  = fmaf(A2, xpf[p] + Dv, HW1);
                    const float x0f = floorf(ix);
                    const float fx1 = ix - x0f;
                    const int   k   = (int)(x0f - t0af);
                    const float* tp = slot + k * CCH;
#pragma unroll
                    for (int c = 0; c < CCH; c++) {
                        const float q0 = tp[c];
                        const float q1 = tp[c + CCH];
                        acc[c][p] = q0 + fx1 * (q1 - q0);
                    }
                }
            } else {                            // y-edge row: uniform m=my
#pragma unroll
                for (int p = 0; p < PXT; p++) {
                    const float ix  = fmaf(A2, xpf[p] + Dv, HW1);
                    const float x0f = floorf(ix);
                    const float fx1 = ix - x0f;
                    const int   k   = (int)(x0f - t0af);
                    const float* tp = slot + k * CCH;
#pragma unroll
                    for (int c = 0; c < CCH; c++) {
                        const float q0 = tp[c];
                        const float q1 = tp[c + CCH];
                        const float sc = q0 + fx1 * (q1 - q0);
                        acc[c][p] = acc[c][p] * omy + my * sc;
                    }
                }
            }
        } else {
            // boundary wave: full reference math with clamps (v11 verified)
#pragma unroll
            for (int p = 0; p < PXT; p++) {
                const float ix  = fmaf(A2, xpf[p] + Dv, HW1);
                const float x0f = floorf(ix);
                const float fx1 = ix - x0f;
                const float fx0 = 1.0f - fx1;
                const float x1f = x0f + 1.0f;
                const float v0  = (x0f >= 0.0f && x0f < (float)WI) ? 1.0f : 0.0f;
                const float v1  = (x1f >= 0.0f && x1f < (float)WI) ? 1.0f : 0.0f;
                const float wx0 = fx0 * v0;
                const float wx1 = fx1 * v1;
                int x0r = (int)fminf(fmaxf(x0f, 0.0f), (float)(WI - 1)) - t0a;
                int x1r = (int)fminf(fmaxf(x1f, 0.0f), (float)(WI - 1)) - t0a;
                x0r = min(max(x0r, 0), lim);
                x1r = min(max(x1r, 0), lim);
                const float m  = my * (wx0 + wx1);
                const float om = 1.0f - m;
#pragma unroll
                for (int c = 0; c < CCH; c++) {
                    const float q0 = slot[x0r * CCH + c];
                    const float q1 = slot[x1r * CCH + c];
                    acc[c][p] = acc[c][p] * om + (q0 * wx0 + q1 * wx1) * m;
                }
            }
        }
    }

#pragma unroll
    for (int c = 0; c < CCH; c++)
        *(float4*)&out[c * (HO * WO) + gbase] =
            make_float4(acc[c][0], acc[c][1], acc[c][2], acc[c][3]);
}

extern "C" void kernel_launch(void* const* d_in, const int* in_sizes, int n_in,
                              void* d_out, int out_size, void* d_ws, size_t ws_size,
                              hipStream_t stream) {
    const float* src  = (const float*)d_in[0];   // [8,3,512,512]
    const float* bg   = (const float*)d_in[1];   // [1,3,2048,2048]
    const float* coor = (const float*)d_in[2];   // [8,4]
    float* out = (float*)d_out;                  // [1,3,2048,2048]
    (void)d_ws; (void)ws_size;

    hipLaunchKernelGGL(diffcomp_v14, dim3(HO), dim3(TPB), 0, stream,
                       src, bg, coor, out);
}